// Round 5
// baseline (88.418 us; speedup 1.0000x reference)
//
#include <hip/hip_runtime.h>
#include <type_traits>

typedef float v2f __attribute__((ext_vector_type(2)));

constexpr int BLOCK = 256;
constexpr int SPT = 2;                     // samples per thread
constexpr int SPB = BLOCK * SPT;           // 512 samples per block
constexpr int HALO_LO = 10;                // l_max(7) + m_max(3)
constexpr int HALO_HI = 3;                 // +m_max for the c (leading) term
constexpr int SIG = SPB + HALO_LO + HALO_HI;

// ---------------- compile-time unroll helper ----------------
template<int I, int N, typename F>
__device__ __forceinline__ void unroll_for(F&& f) {
    if constexpr (I < N) {
        f(std::integral_constant<int, I>{});
        unroll_for<I + 1, N>(static_cast<F&&>(f));
    }
}

// ---------------- kernel 1: fold coefficients ----------------
// W[l][s][k] complex, packed as (re,im) pairs: w2[(l*7+s)*8 + k].
// slot 0 = a[:,l] + b[:,l,0] + c[:,l,0]; slots 1..3 = b m=1..3; 4..6 = c m=1..3.
__global__ void prefold_kernel(
    const float* __restrict__ a_re, const float* __restrict__ a_im,
    const float* __restrict__ b_re, const float* __restrict__ b_im,
    const float* __restrict__ c_re, const float* __restrict__ c_im,
    float* __restrict__ w)
{
    int idx = threadIdx.x;
    if (idx >= 448) return;
    int l = idx / 56;
    int rem = idx - l * 56;
    int s = rem >> 3;
    int k = rem & 7;
    int akl = k * 8 + l;                   // a[k][l]; b/c[k][l][m] = akl*4 + m
    float re, im;
    if (s == 0) {
        re = a_re[akl] + b_re[akl * 4] + c_re[akl * 4];
        im = a_im[akl] + b_im[akl * 4] + c_im[akl * 4];
    } else if (s <= 3) {
        re = b_re[akl * 4 + s];
        im = b_im[akl * 4 + s];
    } else {
        re = c_re[akl * 4 + (s - 3)];
        im = c_im[akl * 4 + (s - 3)];
    }
    w[idx * 2]     = re;
    w[idx * 2 + 1] = im;
}

// ---------------- kernel 2: main GMP ----------------
// y[n] = sum_l x[n-l] * sum_s P_{l,s}(r[n-l+d(s)]),  d: 0,-1,-2,-3,+1,+2,+3
// Two samples per thread: each uniform coefficient s_load feeds two
// independent packed-Horner chains (ILP vs scalar-load latency).
__global__ __launch_bounds__(BLOCK) void gmp_kernel(
    const float* __restrict__ x,
    const v2f* __restrict__ w2,            // folded coefficients (448 pairs)
    float* __restrict__ out, int N)
{
    __shared__ float sxr[SIG], sxi[SIG], sab[SIG];

    const int t = threadIdx.x;
    const int n0 = blockIdx.x * SPB;

    // stage signal + envelope with clipped halo
    const float2* x2 = (const float2*)x;
    for (int j = t; j < SIG; j += BLOCK) {
        int g = n0 - HALO_LO + j;
        g = max(0, min(N - 1, g));
        float2 v = x2[g];
        sxr[j] = v.x;
        sxi[j] = v.y;
        sab[j] = __builtin_amdgcn_sqrtf(fmaf(v.x, v.x, v.y * v.y));
    }
    __syncthreads();

    // register-cache this thread's window (compile-time offsets from 2t)
    const int jb = 2 * t;
    float rv[15];                  // rv[i] = |x| at smem index jb + i
    unroll_for<0, 15>([&](auto I) { rv[I.value] = sab[jb + I.value]; });
    float xr[9], xi[9];            // x at smem index jb + 3 + i
    unroll_for<0, 9>([&](auto I) {
        xr[I.value] = sxr[jb + 3 + I.value];
        xi[I.value] = sxi[jb + 3 + I.value];
    });

    float y0r = 0.f, y0i = 0.f, y1r = 0.f, y1i = 0.f;

    unroll_for<0, 8>([&](auto Lc) {
        constexpr int L = Lc.value;
        v2f S0 = {0.f, 0.f}, S1 = {0.f, 0.f};
        unroll_for<0, 7>([&](auto Sc) {
            constexpr int Sl = Sc.value;
            constexpr int d = (Sl == 0) ? 0 : ((Sl <= 3) ? -Sl : (Sl - 3));
            constexpr int base = (L * 7 + Sl) * 8;    // 8 pairs per slot
            const float r0 = rv[10 - L + d];
            const float r1 = rv[11 - L + d];
            const v2f rr0 = {r0, r0};
            const v2f rr1 = {r1, r1};
            v2f acc0 = w2[base + 7];                  // k = 7
            v2f acc1 = acc0;
            unroll_for<0, 7>([&](auto Kc) {
                constexpr int k = 6 - Kc.value;
                const v2f wk = w2[base + k];
                acc0 = __builtin_elementwise_fma(acc0, rr0, wk);
                acc1 = __builtin_elementwise_fma(acc1, rr1, wk);
            });
            S0 += acc0;
            S1 += acc1;
        });
        {
            const float xre = xr[7 - L], xim = xi[7 - L];
            y0r = fmaf(xre, S0.x, fmaf(-xim, S0.y, y0r));
            y0i = fmaf(xre, S0.y, fmaf( xim, S0.x, y0i));
        }
        {
            const float xre = xr[8 - L], xim = xi[8 - L];
            y1r = fmaf(xre, S1.x, fmaf(-xim, S1.y, y1r));
            y1i = fmaf(xre, S1.y, fmaf( xim, S1.x, y1i));
        }
    });

    const int nb = n0 + 2 * t;
    if (nb + 1 < N) {
        float4* o4 = (float4*)(out + 2 * nb);
        *o4 = make_float4(y0r, y0i, y1r, y1i);
    } else if (nb < N) {
        out[2 * nb]     = y0r;
        out[2 * nb + 1] = y0i;
    }
}

extern "C" void kernel_launch(void* const* d_in, const int* in_sizes, int n_in,
                              void* d_out, int out_size, void* d_ws, size_t ws_size,
                              hipStream_t stream) {
    const float* x    = (const float*)d_in[0];
    const float* a_re = (const float*)d_in[1];
    const float* a_im = (const float*)d_in[2];
    const float* b_re = (const float*)d_in[3];
    const float* b_im = (const float*)d_in[4];
    const float* c_re = (const float*)d_in[5];
    const float* c_im = (const float*)d_in[6];
    float* out = (float*)d_out;
    float* w   = (float*)d_ws;             // 448 * 2 * 4 = 3584 bytes used

    int N = in_sizes[0] / 2;
    prefold_kernel<<<1, 448, 0, stream>>>(a_re, a_im, b_re, b_im, c_re, c_im, w);
    int grid = (N + SPB - 1) / SPB;
    gmp_kernel<<<grid, BLOCK, 0, stream>>>(x, (const v2f*)w, out, N);
}